// Round 1
// baseline (105.719 us; speedup 1.0000x reference)
//
#include <hip/hip_runtime.h>
#include <stdint.h>

// SKA 2D: out[b, g*8+cw, h, w] = sum_{i,j} x[b, g*8+cw, h+i-1, w+j-1] * w[b, cw, 3i+j, h, w]
// B=8, C=64, H=W=128, C_w=8, ks=3, groups=8. fp32. Memory-bound; compulsory ~105 MB HBM.
//
// R3: 16-row tiles (18 staged) cut x halo over-fetch 1.25x -> 1.125x, and a
// bijective XCD-chunk swizzle puts all htiles of each batch b on XCD b so the
// remaining halo duplicate rows are same-L2 hits. LDS 72 KiB -> 2 blocks/CU
// (gfx950 WG-LDS limit is 160 KiB). Stage path unchanged: async
// global_load_lds dwordx4 into an exactly-linear LDS layout, out-of-image rows
// staged CLAMPED with the boundary-tap weights zeroed (garbage * 0 == 0).
// Weights: 18 float4 regs/thread (rows hl and hl+8), reused across all 8
// groups (exact 1x w traffic). Horizontal halos via wave shuffles.

#define SKA_W 128
#define SKA_HW (128 * 128)
#define TILE_ROWS 16
#define STAGE_ROWS 18

typedef float vf4 __attribute__((ext_vector_type(4)));

__global__ __launch_bounds__(256, 2) void SKA_44830868635847_kernel(
        const float* __restrict__ x,
        const float* __restrict__ wgt,
        float* __restrict__ out) {
    __shared__ float lds[8 * STAGE_ROWS * SKA_W];  // 72 KiB -> 2 blocks/CU

    const int t = threadIdx.x;

    // XCD-aware bijective swizzle (512 blocks, 512 % 8 == 0): physical block p
    // dispatches round-robin to XCD p%8; remap so logical ids [64j, 64j+64)
    // (= all cw,htile of batch j) land on XCD j. Adjacent htiles of the same
    // (b,cw) then share their halo rows through one L2.
    const int p = blockIdx.x;
    const int L = (p & 7) * 64 + (p >> 3);
    const int htile = L & 7;             // 8 row-tiles of 16
    const int cw    = (L >> 3) & 7;
    const int b     = L >> 6;
    const int h0    = htile * TILE_ROWS;

    const int w4 = t & 31;               // 32 float4-chunks across W
    const int hl = t >> 5;               // thread owns rows h0+hl and h0+hl+8
    const int w0 = w4 * 4;

    // ---- async stage x: 8 channels x 18 rows x 128 cols, global_load_lds x16.
    // 8*18*32 = 4608 chunks / 256 threads = 18 per thread. LDS dest is
    // wave-uniform base + lane*16 (layout linear in chunk index). Rows clamped
    // at the image edge; boundary taps neutralized via zeroed weights below.
    const float* xb = x + (size_t)(b * 64 + cw) * SKA_HW;
    const int wavebase = t & ~63;
#pragma unroll
    for (int rep = 0; rep < 18; ++rep) {
        int idx = rep * 256 + t;
        int ch  = idx / 576;             // 576 chunks per channel (18 rows x 32)
        int rem = idx - ch * 576;
        int r   = rem >> 5;
        int c4  = rem & 31;
        int xrow = h0 - 1 + r;
        xrow = xrow < 0 ? 0 : (xrow > 127 ? 127 : xrow);   // clamp (see above)
        const float* gsrc = xb + (size_t)ch * 8 * SKA_HW + (size_t)xrow * SKA_W + c4 * 4;
        __builtin_amdgcn_global_load_lds(
            (const __attribute__((address_space(1))) uint32_t*)gsrc,
            (__attribute__((address_space(3))) uint32_t*)&lds[(size_t)(rep * 256 + wavebase) * 4],
            16, 0, 0);
    }

    // ---- weights: 9 float4/thread per owned row (18 total), loaded once,
    // reused across all 8 groups
    const int hA = h0 + hl;              // 0..119
    const int hB = hA + 8;               // 8..127
    const float* wbA = wgt + ((size_t)(b * 8 + cw) * 9) * SKA_HW + (size_t)hA * SKA_W + w0;
    vf4 wvA[9], wvB[9];
#pragma unroll
    for (int k = 0; k < 9; ++k) {
        wvA[k] = *(const vf4*)(wbA + (size_t)k * SKA_HW);
        wvB[k] = *(const vf4*)(wbA + (size_t)k * SKA_HW + 8 * SKA_W);
    }
    // zero boundary taps: row 0 has no i=0 tap, row 127 no i=2 tap
    if (hA == 0)   { wvA[0] = (vf4)(0.f); wvA[1] = (vf4)(0.f); wvA[2] = (vf4)(0.f); }
    if (hB == 127) { wvB[6] = (vf4)(0.f); wvB[7] = (vf4)(0.f); wvB[8] = (vf4)(0.f); }

    __syncthreads();   // drains vmcnt (global_load_lds) before LDS reads

    // ---- compute: per group, 3 row taps per owned row from LDS; horizontal
    // halos via shuffle. Output row h0+rr reads LDS rows rr..rr+2 (LDS row 0
    // is image row h0-1).
    const size_t obaseA = (size_t)(b * 64 + cw) * SKA_HW + (size_t)hA * SKA_W + w0;
#pragma unroll
    for (int g = 0; g < 8; ++g) {
        vf4 accA = (vf4)(0.f);
        vf4 accB = (vf4)(0.f);
#pragma unroll
        for (int i = 0; i < 3; ++i) {
            {   // row A: output row h0+hl
                const float* lrow = &lds[(g * STAGE_ROWS + hl + i) * SKA_W + w0];
                vf4 mid = *(const vf4*)lrow;
                float xl  = __shfl_up(mid.w, 1);
                xl  = (w4 == 0)  ? 0.f : xl;
                float xr4 = __shfl_down(mid.x, 1);
                xr4 = (w4 == 31) ? 0.f : xr4;
                vf4 wl = wvA[i * 3 + 0];
                vf4 wm = wvA[i * 3 + 1];
                vf4 wr = wvA[i * 3 + 2];
                accA.x += wl.x * xl    + wm.x * mid.x + wr.x * mid.y;
                accA.y += wl.y * mid.x + wm.y * mid.y + wr.y * mid.z;
                accA.z += wl.z * mid.y + wm.z * mid.z + wr.z * mid.w;
                accA.w += wl.w * mid.z + wm.w * mid.w + wr.w * xr4;
            }
            {   // row B: output row h0+hl+8
                const float* lrow = &lds[(g * STAGE_ROWS + hl + 8 + i) * SKA_W + w0];
                vf4 mid = *(const vf4*)lrow;
                float xl  = __shfl_up(mid.w, 1);
                xl  = (w4 == 0)  ? 0.f : xl;
                float xr4 = __shfl_down(mid.x, 1);
                xr4 = (w4 == 31) ? 0.f : xr4;
                vf4 wl = wvB[i * 3 + 0];
                vf4 wm = wvB[i * 3 + 1];
                vf4 wr = wvB[i * 3 + 2];
                accB.x += wl.x * xl    + wm.x * mid.x + wr.x * mid.y;
                accB.y += wl.y * mid.x + wm.y * mid.y + wr.y * mid.z;
                accB.z += wl.z * mid.y + wm.z * mid.z + wr.z * mid.w;
                accB.w += wl.w * mid.z + wm.w * mid.w + wr.w * xr4;
            }
        }
        *(vf4*)(out + obaseA + (size_t)g * 8 * SKA_HW) = accA;
        *(vf4*)(out + obaseA + (size_t)g * 8 * SKA_HW + 8 * SKA_W) = accB;
    }
}

extern "C" void kernel_launch(void* const* d_in, const int* in_sizes, int n_in,
                              void* d_out, int out_size, void* d_ws, size_t ws_size,
                              hipStream_t stream) {
    const float* x   = (const float*)d_in[0];  // (8, 64, 128, 128)
    const float* wgt = (const float*)d_in[1];  // (8, 8, 9, 128, 128)
    float* out = (float*)d_out;                // (8, 64, 128, 128)

    // blocks = B * C_w * (H / TILE_ROWS) = 8*8*8 = 512, 256 threads each
    SKA_44830868635847_kernel<<<512, 256, 0, stream>>>(x, wgt, out);
}

// Round 2
// 105.027 us; speedup vs baseline: 1.0066x; 1.0066x over previous
//
#include <hip/hip_runtime.h>
#include <stdint.h>

// SKA 2D: out[b, g*8+cw, h, w] = sum_{i,j} x[b, g*8+cw, h+i-1, w+j-1] * w[b, cw, 3i+j, h, w]
// B=8, C=64, H=W=128, C_w=8, ks=3, groups=8. fp32. Memory-bound, ideal ~105 MB HBM.
//
// R4 = R2-proven base (8-row tiles, 40 KiB LDS, 4 blocks/CU, 1024 blocks =
// exactly device-filling) + bijective XCD swizzle ONLY. R3's 16-row tile
// halved occupancy (72 KiB LDS) and regressed; reverted. The swizzle maps all
// 128 blocks of batch b onto XCD b so htile-adjacent blocks' shared halo rows
// (the 1.25x x over-fetch) become same-L2 hits instead of L3/HBM re-fetches.
//
// Stage: async global_load_lds dwordx4, LDS layout exactly linear (byte off =
// chunk*16 = wave-uniform base + lane*16). Out-of-image rows staged CLAMPED,
// boundary-tap weights zeroed (garbage * 0 == 0) -> no predication on DMA.
// Weights: 9 float4 regs/thread, reused across all 8 groups (exact 1x w
// traffic). Horizontal halos via wave shuffles.

#define SKA_W 128
#define SKA_HW (128 * 128)
#define TILE_ROWS 8
#define STAGE_ROWS 10

typedef float vf4 __attribute__((ext_vector_type(4)));

__global__ __launch_bounds__(256, 4) void SKA_44830868635847_kernel(
        const float* __restrict__ x,
        const float* __restrict__ wgt,
        float* __restrict__ out) {
    __shared__ float lds[8 * STAGE_ROWS * SKA_W];  // 40 KiB -> 4 blocks/CU

    const int t = threadIdx.x;

    // XCD-aware bijective swizzle (1024 blocks, 1024 % 8 == 0): physical block
    // p dispatches round-robin to XCD p%8; remap so logical ids [128j, 128j+128)
    // (= all cw,htile of batch j) land on XCD j. htile-adjacent blocks of the
    // same (b,cw) then share their halo rows through one L2.
    const int p = blockIdx.x;
    const int L = (p & 7) * 128 + (p >> 3);
    const int htile = L & 15;            // 16 row-tiles of 8
    const int cw    = (L >> 4) & 7;
    const int b     = L >> 7;
    const int h0    = htile * TILE_ROWS;

    const int w4 = t & 31;               // 32 float4-chunks across W
    const int hl = t >> 5;               // 8 rows per block
    const int h  = h0 + hl;
    const int w0 = w4 * 4;

    // ---- async stage x: 8 channels x 10 rows x 128 cols, global_load_lds x16.
    // 2560 chunks / 256 threads = 10 per thread. LDS dest is wave-uniform
    // base + lane*16 (layout is linear in chunk index). Rows clamped at the
    // image edge; boundary taps neutralized via zeroed weights below.
    const float* xb = x + (size_t)(b * 64 + cw) * SKA_HW;
    const int wavebase = t & ~63;
#pragma unroll
    for (int rep = 0; rep < 10; ++rep) {
        int idx = rep * 256 + t;
        int ch  = idx / 320;             // 320 chunks per channel (10 rows x 32)
        int rem = idx - ch * 320;
        int r   = rem >> 5;
        int c4  = rem & 31;
        int xrow = h0 - 1 + r;
        xrow = xrow < 0 ? 0 : (xrow > 127 ? 127 : xrow);   // clamp (see above)
        const float* gsrc = xb + (size_t)ch * 8 * SKA_HW + (size_t)xrow * SKA_W + c4 * 4;
        __builtin_amdgcn_global_load_lds(
            (const __attribute__((address_space(1))) uint32_t*)gsrc,
            (__attribute__((address_space(3))) uint32_t*)&lds[(size_t)(rep * 256 + wavebase) * 4],
            16, 0, 0);
    }

    // ---- weights: 9 float4/thread, loaded once, reused across all 8 groups
    const float* wbase = wgt + ((size_t)(b * 8 + cw) * 9) * SKA_HW + (size_t)h * SKA_W + w0;
    vf4 wv[9];
#pragma unroll
    for (int k = 0; k < 9; ++k)
        wv[k] = *(const vf4*)(wbase + (size_t)k * SKA_HW);
    // zero boundary taps: row h==0 has no i=0 tap, h==127 no i=2 tap
    if (h == 0)   { wv[0] = (vf4)(0.f); wv[1] = (vf4)(0.f); wv[2] = (vf4)(0.f); }
    if (h == 127) { wv[6] = (vf4)(0.f); wv[7] = (vf4)(0.f); wv[8] = (vf4)(0.f); }

    __syncthreads();   // drains vmcnt (global_load_lds) before LDS reads

    // ---- compute: per group, 3 row taps from LDS; horizontal halos via shuffle
    const size_t obase = (size_t)(b * 64 + cw) * SKA_HW + (size_t)h * SKA_W + w0;
#pragma unroll
    for (int g = 0; g < 8; ++g) {
        vf4 acc = (vf4)(0.f);
#pragma unroll
        for (int i = 0; i < 3; ++i) {
            const float* lrow = &lds[(g * STAGE_ROWS + hl + i) * SKA_W + w0];
            vf4 mid = *(const vf4*)lrow;
            // halos from lane-adjacent chunk (w4 +- 1); lanes 0/32 have w4==0,
            // lanes 31/63 have w4==31, so cross-row shuffles are always masked.
            float xl  = __shfl_up(mid.w, 1);
            xl  = (w4 == 0)  ? 0.f : xl;
            float xr4 = __shfl_down(mid.x, 1);
            xr4 = (w4 == 31) ? 0.f : xr4;
            vf4 wl = wv[i * 3 + 0];
            vf4 wm = wv[i * 3 + 1];
            vf4 wr = wv[i * 3 + 2];
            acc.x += wl.x * xl    + wm.x * mid.x + wr.x * mid.y;
            acc.y += wl.y * mid.x + wm.y * mid.y + wr.y * mid.z;
            acc.z += wl.z * mid.y + wm.z * mid.z + wr.z * mid.w;
            acc.w += wl.w * mid.z + wm.w * mid.w + wr.w * xr4;
        }
        *(vf4*)(out + obase + (size_t)g * 8 * SKA_HW) = acc;
    }
}

extern "C" void kernel_launch(void* const* d_in, const int* in_sizes, int n_in,
                              void* d_out, int out_size, void* d_ws, size_t ws_size,
                              hipStream_t stream) {
    const float* x   = (const float*)d_in[0];  // (8, 64, 128, 128)
    const float* wgt = (const float*)d_in[1];  // (8, 8, 9, 128, 128)
    float* out = (float*)d_out;                // (8, 64, 128, 128)

    // blocks = B * C_w * (H / TILE_ROWS) = 8*8*16 = 1024, 256 threads each
    SKA_44830868635847_kernel<<<1024, 256, 0, stream>>>(x, wgt, out);
}

// Round 3
// 103.444 us; speedup vs baseline: 1.0220x; 1.0153x over previous
//
#include <hip/hip_runtime.h>
#include <stdint.h>

// SKA 2D: out[b, g*8+cw, h, w] = sum_{i,j} x[b, g*8+cw, h+i-1, w+j-1] * w[b, cw, 3i+j, h, w]
// B=8, C=64, H=W=128, C_w=8, ks=3, groups=8. fp32. Memory-bound, compulsory ~105 MB HBM.
//
// FINAL (R5 = exact R2): block = (b, cw, 8-row tile), 256 threads, 40 KiB LDS
// (8 ch x 10 rows x 128 cols), 4 blocks/CU, 1024 blocks = exactly device-filling.
// Verified dead ends (R3/R4): 16-row tiles (halo -10%) halve occupancy and
// regress; XCD swizzle is neutral — the 256 MB L3 already absorbs all halo
// re-fetches, so HBM traffic is compulsory-only in every variant. Kernel runs
// at ~85-90% of the 6.29 TB/s mixed-stream ceiling; remaining headline gap is
// harness poison-fills (2 x ~41.4 us at 81% peak) + graph gaps.
//
// Stage: async global_load_lds dwordx4, LDS layout exactly linear (byte off =
// chunk*16 = wave-uniform base + lane*16). Out-of-image rows staged CLAMPED,
// boundary-tap weights zeroed (garbage * 0 == 0) -> no predication on DMA.
// Weights: 9 float4 regs/thread, reused across all 8 groups (exact 1x w
// traffic). Horizontal halos via wave shuffles.

#define SKA_W 128
#define SKA_HW (128 * 128)
#define TILE_ROWS 8
#define STAGE_ROWS 10

typedef float vf4 __attribute__((ext_vector_type(4)));

__global__ __launch_bounds__(256, 4) void SKA_44830868635847_kernel(
        const float* __restrict__ x,
        const float* __restrict__ wgt,
        float* __restrict__ out) {
    __shared__ float lds[8 * STAGE_ROWS * SKA_W];  // 40 KiB -> 4 blocks/CU

    const int t     = threadIdx.x;
    const int bid   = blockIdx.x;
    const int htile = bid & 15;          // 16 row-tiles of 8
    const int cw    = (bid >> 4) & 7;
    const int b     = bid >> 7;
    const int h0    = htile * TILE_ROWS;

    const int w4 = t & 31;               // 32 float4-chunks across W
    const int hl = t >> 5;               // 8 rows per block
    const int h  = h0 + hl;
    const int w0 = w4 * 4;

    // ---- async stage x: 8 channels x 10 rows x 128 cols, global_load_lds x16.
    // 2560 chunks / 256 threads = 10 per thread. LDS dest is wave-uniform
    // base + lane*16 (layout is linear in chunk index). Rows clamped at the
    // image edge; boundary taps neutralized via zeroed weights below.
    const float* xb = x + (size_t)(b * 64 + cw) * SKA_HW;
    const int wavebase = t & ~63;
#pragma unroll
    for (int rep = 0; rep < 10; ++rep) {
        int idx = rep * 256 + t;
        int ch  = idx / 320;             // 320 chunks per channel (10 rows x 32)
        int rem = idx - ch * 320;
        int r   = rem >> 5;
        int c4  = rem & 31;
        int xrow = h0 - 1 + r;
        xrow = xrow < 0 ? 0 : (xrow > 127 ? 127 : xrow);   // clamp (see above)
        const float* gsrc = xb + (size_t)ch * 8 * SKA_HW + (size_t)xrow * SKA_W + c4 * 4;
        __builtin_amdgcn_global_load_lds(
            (const __attribute__((address_space(1))) uint32_t*)gsrc,
            (__attribute__((address_space(3))) uint32_t*)&lds[(size_t)(rep * 256 + wavebase) * 4],
            16, 0, 0);
    }

    // ---- weights: 9 float4/thread, loaded once, reused across all 8 groups
    const float* wbase = wgt + ((size_t)(b * 8 + cw) * 9) * SKA_HW + (size_t)h * SKA_W + w0;
    vf4 wv[9];
#pragma unroll
    for (int k = 0; k < 9; ++k)
        wv[k] = *(const vf4*)(wbase + (size_t)k * SKA_HW);
    // zero boundary taps: row h==0 has no i=0 tap, h==127 no i=2 tap
    if (h == 0)   { wv[0] = (vf4)(0.f); wv[1] = (vf4)(0.f); wv[2] = (vf4)(0.f); }
    if (h == 127) { wv[6] = (vf4)(0.f); wv[7] = (vf4)(0.f); wv[8] = (vf4)(0.f); }

    __syncthreads();   // drains vmcnt (global_load_lds) before LDS reads

    // ---- compute: per group, 3 row taps from LDS; horizontal halos via shuffle
    const size_t obase = (size_t)(b * 64 + cw) * SKA_HW + (size_t)h * SKA_W + w0;
#pragma unroll
    for (int g = 0; g < 8; ++g) {
        vf4 acc = (vf4)(0.f);
#pragma unroll
        for (int i = 0; i < 3; ++i) {
            const float* lrow = &lds[(g * STAGE_ROWS + hl + i) * SKA_W + w0];
            vf4 mid = *(const vf4*)lrow;
            // halos from lane-adjacent chunk (w4 +- 1); lanes 0/32 have w4==0,
            // lanes 31/63 have w4==31, so cross-row shuffles are always masked.
            float xl  = __shfl_up(mid.w, 1);
            xl  = (w4 == 0)  ? 0.f : xl;
            float xr4 = __shfl_down(mid.x, 1);
            xr4 = (w4 == 31) ? 0.f : xr4;
            vf4 wl = wv[i * 3 + 0];
            vf4 wm = wv[i * 3 + 1];
            vf4 wr = wv[i * 3 + 2];
            acc.x += wl.x * xl    + wm.x * mid.x + wr.x * mid.y;
            acc.y += wl.y * mid.x + wm.y * mid.y + wr.y * mid.z;
            acc.z += wl.z * mid.y + wm.z * mid.z + wr.z * mid.w;
            acc.w += wl.w * mid.z + wm.w * mid.w + wr.w * xr4;
        }
        *(vf4*)(out + obase + (size_t)g * 8 * SKA_HW) = acc;
    }
}

extern "C" void kernel_launch(void* const* d_in, const int* in_sizes, int n_in,
                              void* d_out, int out_size, void* d_ws, size_t ws_size,
                              hipStream_t stream) {
    const float* x   = (const float*)d_in[0];  // (8, 64, 128, 128)
    const float* wgt = (const float*)d_in[1];  // (8, 8, 9, 128, 128)
    float* out = (float*)d_out;                // (8, 64, 128, 128)

    // blocks = B * C_w * (H / TILE_ROWS) = 8*8*16 = 1024, 256 threads each
    SKA_44830868635847_kernel<<<1024, 256, 0, stream>>>(x, wgt, out);
}